// Round 14
// baseline (409.794 us; speedup 1.0000x reference)
//
#include <hip/hip_runtime.h>
#include <hip/hip_bf16.h>
#include <cstdint>
#include <cstddef>

#define DI __device__ __forceinline__

typedef __attribute__((ext_vector_type(8))) short short8;
typedef __attribute__((ext_vector_type(4))) float f32x4;

static constexpr int Bb = 8192, Dd = 512, Hh = 1024;

DI short f2b(float f) {
  union { __hip_bfloat16 h; short s; } u;
  u.h = __float2bfloat16(f);
  return u.s;
}

DI float sigm(float x) {
  float e = __builtin_amdgcn_exp2f(-1.4426950408889634f * x);
  return __builtin_amdgcn_rcpf(1.0f + e);
}
DI float tanh_(float x) {
  float xc = fminf(fmaxf(x, -20.0f), 20.0f);
  float e = __builtin_amdgcn_exp2f(-2.8853900817779268f * xc);  // exp(-2x)
  return (1.0f - e) * __builtin_amdgcn_rcpf(1.0f + e);
}

DI void gload16(const void* g, void* l) {
  __builtin_amdgcn_global_load_lds(
      (const __attribute__((address_space(1))) uint32_t*)g,
      (__attribute__((address_space(3))) uint32_t*)l, 16, 0, 0);
}

// ---------------- prep kernels ----------------

// fused: A0[row] = [x | h0*m0] (192 thr) and A1[row][1024:] = h1*m1 (128 thr)
__global__ void conv_acts(const float* __restrict__ x, const float* __restrict__ h0,
                          const float* __restrict__ m0, const float* __restrict__ h1,
                          const float* __restrict__ m1,
                          short* __restrict__ A0, short* __restrict__ A1) {
  const int row = blockIdx.x, t = threadIdx.x;  // block=320
  float v[8];
  if (t < 192) {
    if (t < 64) {
      const float4* p = (const float4*)(x + (size_t)row * Dd + t * 8);
      float4 a = p[0], b = p[1];
      v[0] = a.x; v[1] = a.y; v[2] = a.z; v[3] = a.w;
      v[4] = b.x; v[5] = b.y; v[6] = b.z; v[7] = b.w;
    } else {
      const int j = t * 8 - 512;
      const float4* ph = (const float4*)(h0 + (size_t)row * Hh + j);
      const float4* pm = (const float4*)(m0 + (size_t)row * Hh + j);
      float4 a = ph[0], b = ph[1], ma = pm[0], mb = pm[1];
      v[0] = a.x * ma.x; v[1] = a.y * ma.y; v[2] = a.z * ma.z; v[3] = a.w * ma.w;
      v[4] = b.x * mb.x; v[5] = b.y * mb.y; v[6] = b.z * mb.z; v[7] = b.w * mb.w;
    }
    short8 o;
    #pragma unroll
    for (int q = 0; q < 8; q++) o[q] = f2b(v[q]);
    *(short8*)(A0 + (size_t)row * 1536 + t * 8) = o;
  } else {
    const int j = (t - 192) * 8;
    const float4* ph = (const float4*)(h1 + (size_t)row * Hh + j);
    const float4* pm = (const float4*)(m1 + (size_t)row * Hh + j);
    float4 a = ph[0], b = ph[1], ma = pm[0], mb = pm[1];
    v[0] = a.x * ma.x; v[1] = a.y * ma.y; v[2] = a.z * ma.z; v[3] = a.w * ma.w;
    v[4] = b.x * mb.x; v[5] = b.y * mb.y; v[6] = b.z * mb.z; v[7] = b.w * mb.w;
    short8 o;
    #pragma unroll
    for (int q = 0; q < 8; q++) o[q] = f2b(v[q]);
    *(short8*)(A1 + (size_t)row * 2048 + 1024 + j) = o;
  }
}

// all 8 gate-weight transposes in one launch: z = layer*4 + gate
__global__ void transpose_all(
    const float* __restrict__ w00, const float* __restrict__ w01,
    const float* __restrict__ w02, const float* __restrict__ w03,
    const float* __restrict__ w10, const float* __restrict__ w11,
    const float* __restrict__ w12, const float* __restrict__ w13,
    short* __restrict__ WT0, short* __restrict__ WT1) {
  __shared__ float t[64][65];
  const int z = blockIdx.z;
  const int layer = z >> 2, g = z & 3;
  const int K = layer ? 2048 : 1536;
  const int k0 = blockIdx.x * 64;
  if (k0 >= K) return;
  const float* src;
  switch (z) {
    case 0: src = w00; break; case 1: src = w01; break;
    case 2: src = w02; break; case 3: src = w03; break;
    case 4: src = w10; break; case 5: src = w11; break;
    case 6: src = w12; break; default: src = w13; break;
  }
  short* dst = layer ? WT1 : WT0;
  const int n0 = blockIdx.y * 64;
  const int tid = threadIdx.x;           // 256
  const int r = tid >> 2, c0 = (tid & 3) * 16;
  const float* s = src + (size_t)(k0 + r) * 1024 + n0 + c0;
  #pragma unroll
  for (int q = 0; q < 16; q += 4) {
    float4 v = *(const float4*)(s + q);
    t[r][c0 + q + 0] = v.x; t[r][c0 + q + 1] = v.y;
    t[r][c0 + q + 2] = v.z; t[r][c0 + q + 3] = v.w;
  }
  __syncthreads();
  const int n = n0 + r;
  const int j = (n >> 4) * 64 + g * 16 + (n & 15);
  short8 o0, o1;
  #pragma unroll
  for (int q = 0; q < 8; q++) o0[q] = f2b(t[c0 + q][r]);
  #pragma unroll
  for (int q = 0; q < 8; q++) o1[q] = f2b(t[c0 + 8 + q][r]);
  short* d = dst + (size_t)j * K + k0 + c0;
  *(short8*)d = o0;
  *((short8*)d + 1) = o1;
}

// fused MLP prep: [0,1024) Wm1->bf16 | [1024,1152) Wm2^T | [1152,1168) bp
__global__ void mlp_prep(const float* __restrict__ Wm1, short* __restrict__ Wm1b,
                         const float* __restrict__ Wm2, short* __restrict__ Wm2T,
                         const float* __restrict__ bm1, const float* __restrict__ bm2,
                         float* __restrict__ bp) {
  __shared__ float t[64][65];
  const int b = blockIdx.x, tid = threadIdx.x;
  if (b < 1024) {
    const int id = b * 256 + tid;          // 262144 groups of 8
    const float4* p = (const float4*)(Wm1 + (size_t)id * 8);
    float4 a = p[0], bb = p[1];
    short8 o;
    o[0] = f2b(a.x); o[1] = f2b(a.y); o[2] = f2b(a.z); o[3] = f2b(a.w);
    o[4] = f2b(bb.x); o[5] = f2b(bb.y); o[6] = f2b(bb.z); o[7] = f2b(bb.w);
    *(short8*)(Wm1b + (size_t)id * 8) = o;
  } else if (b < 1152) {
    const int b2 = b - 1024;
    const int k0 = (b2 & 31) * 64, n0 = (b2 >> 5) * 64;   // N=256, K=2048
    const int r = tid >> 2, c0 = (tid & 3) * 16;
    const float* s = Wm2 + (size_t)(k0 + r) * 256 + n0 + c0;
    #pragma unroll
    for (int q = 0; q < 16; q += 4) {
      float4 v = *(const float4*)(s + q);
      t[r][c0 + q + 0] = v.x; t[r][c0 + q + 1] = v.y;
      t[r][c0 + q + 2] = v.z; t[r][c0 + q + 3] = v.w;
    }
    __syncthreads();
    const int n = n0 + r;
    short8 o0, o1;
    #pragma unroll
    for (int q = 0; q < 8; q++) o0[q] = f2b(t[c0 + q][r]);
    #pragma unroll
    for (int q = 0; q < 8; q++) o1[q] = f2b(t[c0 + 8 + q][r]);
    short* d = Wm2T + (size_t)n * 2048 + k0 + c0;
    *(short8*)d = o0;
    *((short8*)d + 1) = o1;
  } else {
    // bp[o] = bm2[o] + sum_k bm1[k]*Wm2[k][o]; 16 blocks x 16 o each, no atomics
    __shared__ float red[16][17];
    const int o0 = (b - 1152) * 16;
    const int oo = tid & 15, kk = tid >> 4;   // 16 x 16
    float s = 0.f;
    const int kbase = kk * 128;
    #pragma unroll 4
    for (int k = 0; k < 128; k++)
      s += bm1[kbase + k] * Wm2[(size_t)(kbase + k) * 256 + o0 + oo];
    red[kk][oo] = s;
    __syncthreads();
    if (tid < 16) {
      float acc = bm2[o0 + tid];
      #pragma unroll
      for (int j = 0; j < 16; j++) acc += red[j][tid];
      bp[o0 + tid] = acc;
    }
  }
}

// ---------------- small GEMM (m97-style 128x128): WpT build only ----------------
__global__ __launch_bounds__(256) void gemm_bt0(
    const short* __restrict__ A, const short* __restrict__ Bt, int K,
    short* __restrict__ Cb, int ldc) {
  __shared__ __align__(16) short sA[128 * 32];
  __shared__ __align__(16) short sB[128 * 32];
  const int tid = threadIdx.x;
  const int lane = tid & 63;
  const int wave = tid >> 6;
  const int wm = wave >> 1, wn = wave & 1;
  const int bm = blockIdx.x, bn = blockIdx.y;
  const int lr = lane & 15, lq = lane >> 4;

  f32x4 acc[4][4] = {};

  const short* pA = A + ((size_t)(bm * 128 + (tid >> 2))) * K + (tid & 3) * 8;
  const short* pB = Bt + ((size_t)(bn * 128 + (tid >> 2))) * K + (tid & 3) * 8;
  short* lA = sA + tid * 8;
  short* lB = sB + tid * 8;
  const int aoff = (wm * 64 + lr) * 32 + lq * 8;
  const int boff = (wn * 64 + lr) * 32 + lq * 8;

  for (int k0 = 0; k0 < K; k0 += 32) {
    gload16(pA + k0, lA);
    gload16(pA + (size_t)64 * K + k0, lA + 2048);
    gload16(pB + k0, lB);
    gload16(pB + (size_t)64 * K + k0, lB + 2048);
    __syncthreads();
    short8 af[4], bv[4];
    #pragma unroll
    for (int m = 0; m < 4; m++) af[m] = *(const short8*)&sA[aoff + m * 512];
    #pragma unroll
    for (int n = 0; n < 4; n++) bv[n] = *(const short8*)&sB[boff + n * 512];
    #pragma unroll
    for (int m = 0; m < 4; m++)
      #pragma unroll
      for (int n = 0; n < 4; n++)
        acc[m][n] = __builtin_amdgcn_mfma_f32_16x16x32_bf16(af[m], bv[n], acc[m][n], 0, 0, 0);
    __syncthreads();
  }

  const int crow0 = bm * 128 + wm * 64 + lq * 4;
  const int ccol0 = bn * 128 + wn * 64 + lr;
  #pragma unroll
  for (int m = 0; m < 4; m++)
    #pragma unroll
    for (int r = 0; r < 4; r++) {
      const int row = crow0 + m * 16 + r;
      #pragma unroll
      for (int n = 0; n < 4; n++)
        Cb[(size_t)row * ldc + ccol0 + n * 16] = f2b(acc[m][n][r]);
    }
}

// ---------- output GEMM: 64x128 tile, 256 blocks ----------
__global__ __launch_bounds__(256) void gemm_out(
    const short* __restrict__ A, const short* __restrict__ Bt, int K,
    float* __restrict__ outp, const float* __restrict__ bpv) {
  __shared__ __align__(16) short sA[64 * 32];
  __shared__ __align__(16) short sB[128 * 32];
  const int tid = threadIdx.x;
  const int lane = tid & 63;
  const int wn = tid >> 6;                 // 4 waves, each 64 rows x 32 cols
  const int bm = blockIdx.x, bn = blockIdx.y;
  const int lr = lane & 15, lq = lane >> 4;

  f32x4 acc[4][2] = {};

  const short* pA = A + ((size_t)(bm * 64 + (tid >> 2))) * K + (tid & 3) * 8;
  const short* pB = Bt + ((size_t)(bn * 128 + (tid >> 2))) * K + (tid & 3) * 8;
  short* lA = sA + tid * 8;
  short* lB = sB + tid * 8;
  const int boff = (wn * 32 + lr) * 32 + lq * 8;

  for (int k0 = 0; k0 < K; k0 += 32) {
    gload16(pA + k0, lA);
    gload16(pB + k0, lB);
    gload16(pB + (size_t)64 * K + k0, lB + 2048);
    __syncthreads();
    short8 af[4], bv[2];
    #pragma unroll
    for (int m = 0; m < 4; m++) af[m] = *(const short8*)&sA[(m * 16 + lr) * 32 + lq * 8];
    #pragma unroll
    for (int n = 0; n < 2; n++) bv[n] = *(const short8*)&sB[boff + n * 512];
    #pragma unroll
    for (int m = 0; m < 4; m++)
      #pragma unroll
      for (int n = 0; n < 2; n++)
        acc[m][n] = __builtin_amdgcn_mfma_f32_16x16x32_bf16(af[m], bv[n], acc[m][n], 0, 0, 0);
    __syncthreads();
  }

  const int crow0 = bm * 64 + lq * 4;
  const int ccol0 = bn * 128 + wn * 32 + lr;
  float bvv[2];
  #pragma unroll
  for (int n = 0; n < 2; n++) bvv[n] = bpv[ccol0 + n * 16];
  #pragma unroll
  for (int m = 0; m < 4; m++)
    #pragma unroll
    for (int r = 0; r < 4; r++) {
      const int row = crow0 + m * 16 + r;
      #pragma unroll
      for (int n = 0; n < 2; n++)
        outp[(size_t)row * 256 + ccol0 + n * 16] = acc[m][n][r] + bvv[n];
    }
}

// ---- 256x256 8-phase LSTM GEMM: cross-phase fragment pipeline ----
// R8 skeleton + fragment ds_reads issued ONE PHASE EARLY (named ping-pong
// avA/avB, bv0/bv1). Counted lgkmcnt(4|12) lets each MM overlap the next
// phase's LDS reads (MFMA pipe ~620 cyc/CU and LDS pipe ~576 cyc/CU are
// separate; R8 serialized them). Since buf1's consume-reads move into P4
// (buf0's into P8), the RAW {vmcnt;barrier} pairs move one phase earlier:
// VM4@P3 drains buf1's 8 loads (leaves P2,P3's 4); VM4@P7 drains buf0(t2)'s
// 8 (leaves P6,P7's 4). Slot-by-slot WAR audit: every slot's last read is
// lgkm-complete >=1 phase before its re-stage issue. Steady-state invariant:
// 6 outstanding at P1 entry (buf1 B0,B1,A0), identical to R8.

#define STA(buf, h, kt) { const short* s_ = gA + (size_t)(h) * 64 * K + (size_t)(kt) * 64; \
    gload16(s_ + aS0, &sA[buf][h][tid * 8]);                                               \
    gload16(s_ + aS1, &sA[buf][h][4096 + tid * 8]); }
#define STB(buf, h, kt) { const short* s_ = gB + (size_t)(h) * 128 * K + (size_t)(kt) * 64; \
    gload16(s_ + bS0, &sB[buf][h][tid * 8]);                                                \
    gload16(s_ + bS1, &sB[buf][h][4096 + tid * 8]); }

#define LDB(buf, bvx) {                                           \
    const short* bb = &sB[buf][bh][brb];                          \
    _Pragma("unroll") for (int n = 0; n < 4; n++) {               \
      bvx[n][0] = *(const short8*)(bb + n * 1024 + sw0);          \
      bvx[n][1] = *(const short8*)(bb + n * 1024 + sw1); } }

#define LDA_(buf, q, av) {                                        \
    const short* ab = &sA[buf][(q) >> 1][arb + ((q) & 1) * 2048]; \
    av[0][0] = *(const short8*)(ab + sw0);                        \
    av[0][1] = *(const short8*)(ab + sw1);                        \
    av[1][0] = *(const short8*)(ab + 1024 + sw0);                 \
    av[1][1] = *(const short8*)(ab + 1024 + sw1); }

#define MM(q, av, bvx) {                                          \
    __builtin_amdgcn_s_setprio(1);                                \
    _Pragma("unroll") for (int m = 0; m < 2; m++)                 \
    _Pragma("unroll") for (int n = 0; n < 4; n++) {               \
      acc[2*(q)+m][n] = __builtin_amdgcn_mfma_f32_16x16x32_bf16(av[m][0], bvx[n][0], acc[2*(q)+m][n], 0, 0, 0); \
      acc[2*(q)+m][n] = __builtin_amdgcn_mfma_f32_16x16x32_bf16(av[m][1], bvx[n][1], acc[2*(q)+m][n], 0, 0, 0); } \
    __builtin_amdgcn_s_setprio(0); }

#define BARR()  __builtin_amdgcn_s_barrier()
#define VM6()   asm volatile("s_waitcnt vmcnt(6)")
#define VM4()   asm volatile("s_waitcnt vmcnt(4)")
#define LGK4()  asm volatile("s_waitcnt lgkmcnt(4)")
#define LGK12() asm volatile("s_waitcnt lgkmcnt(12)")

__global__ __launch_bounds__(512, 2) void gemm8_lstm(
    const short* __restrict__ A, const short* __restrict__ Bt, const int K,
    const float* __restrict__ cprev, float* __restrict__ hout,
    float* __restrict__ cout, short* __restrict__ anext, const int ldan,
    const float* __restrict__ mask,
    const float* __restrict__ bF, const float* __restrict__ bI,
    const float* __restrict__ bC, const float* __restrict__ bO) {
  __shared__ __align__(16) short sA[2][2][8192];
  __shared__ __align__(16) short sB[2][2][8192];
  const int tid = threadIdx.x;
  const int lane = tid & 63, wid = tid >> 6;
  const int wr = wid >> 2, wc = wid & 3;
  const int lr = lane & 15, lq = lane >> 4;
  const int bm = blockIdx.x, bn = blockIdx.y;

  const int NT = K >> 6;        // BK=64 tiles
  const int NIT = NT >> 1;

  // staging source offsets (inverse-swizzled global addresses)
  const int r0 = tid >> 3;
  const int csw = (tid & 7) ^ (r0 & 7);
  const int growA0 = ((r0 >> 5) & 1) * 32 + (r0 & 31);
  const int growA1 = 128 + growA0;
  const size_t aS0 = (size_t)growA0 * K + csw * 8;
  const size_t aS1 = (size_t)growA1 * K + csw * 8;
  const size_t bS0 = (size_t)r0 * K + csw * 8;
  const size_t bS1 = (size_t)(r0 + 64) * K + csw * 8;
  const short* gA = A + (size_t)bm * 256 * K;
  const short* gB = Bt + (size_t)bn * 256 * K;

  // ds_read offsets
  const int arb = (wr * 64 + lr) * 64;
  const int brb = ((wc & 1) * 64 + lr) * 64;
  const int bh = wc >> 1;
  const int sw0 = ((lq) ^ (lr & 7)) * 8;
  const int sw1 = ((4 + lq) ^ (lr & 7)) * 8;

  f32x4 acc[8][4] = {};
  short8 bv0[4][2], bv1[4][2];
  short8 avA[2][2], avB[2][2];

  // prologue: buf0 full (8 loads) + buf1 {B0,B1,A0} (6 loads); wait buf0
  STB(0, 0, 0); STB(0, 1, 0); STA(0, 0, 0); STA(0, 1, 0);
  STB(1, 0, 1); STB(1, 1, 1); STA(1, 0, 1);
  VM6(); BARR();
  // pre-read for P1's MM (12 lgkm in flight)
  LDB(0, bv0); LDA_(0, 0, avA);

  for (int it = 0; it < NIT; ++it) {
    const int k1 = 2 * it + 1;
    int t2 = 2 * it + 2; if (t2 >= NT) t2 = 0;
    int t3 = 2 * it + 3; if (t3 >= NT) t3 = 1;
    // P1: rd q1->avB; stage buf1.A1(k1); MM q0(avA,bv0)
    LDA_(0, 1, avB); STA(1, 1, k1); BARR(); LGK4(); MM(0, avA, bv0); BARR();
    // P2: rd q2->avA; stage buf0.B0(t2); MM q1(avB,bv0)
    LDA_(0, 2, avA); STB(0, 0, t2); BARR(); LGK4(); MM(1, avB, bv0); BARR();
    // P3: rd q3->avB; stage buf0.B1(t2); VM4 -> buf1 complete; MM q2
    LDA_(0, 3, avB); STB(0, 1, t2); VM4(); BARR(); LGK4(); MM(2, avA, bv0); BARR();
    // P4: rd buf1 B->bv1 + q0->avA (12 rds); stage buf0.A0(t2); MM q3(avB,bv0)
    LDB(1, bv1); LDA_(1, 0, avA); STA(0, 0, t2); BARR(); LGK12(); MM(3, avB, bv0); BARR();
    // P5: rd q1->avB; stage buf0.A1(t2); MM q0(avA,bv1)
    LDA_(1, 1, avB); STA(0, 1, t2); BARR(); LGK4(); MM(0, avA, bv1); BARR();
    // P6: rd q2->avA; stage buf1.B0(t3); MM q1(avB,bv1)
    LDA_(1, 2, avA); STB(1, 0, t3); BARR(); LGK4(); MM(1, avB, bv1); BARR();
    // P7: rd q3->avB; stage buf1.B1(t3); VM4 -> buf0(t2) complete; MM q2
    LDA_(1, 3, avB); STB(1, 1, t3); VM4(); BARR(); LGK4(); MM(2, avA, bv1); BARR();
    // P8: rd next-iter buf0 B->bv0 + q0->avA; stage buf1.A0(t3); MM q3(avB,bv1)
    LDB(0, bv0); LDA_(0, 0, avA); STA(1, 0, t3); BARR(); LGK12(); MM(3, avB, bv1); BARR();
  }

  // ---- LSTM cell epilogue: fast math + pipelined cprev/mask prefetch ----
  const int n = (bn * 4 + wc) * 16 + lr;
  const float bf_ = bF[n], bi_ = bI[n], bc_ = bC[n], bo_ = bO[n];
  const int row0 = bm * 256 + wr * 128 + lq * 4;

  float cp[4], mk[4], cpn[4], mkn[4];
  #pragma unroll
  for (int rr = 0; rr < 4; rr++) {
    const size_t idx = (size_t)(row0 + rr) * 1024 + n;
    cp[rr] = cprev[idx];
    mk[rr] = mask ? mask[idx] : 1.0f;
  }
  #pragma unroll
  for (int mf = 0; mf < 8; mf++) {
    if (mf < 7) {
      #pragma unroll
      for (int rr = 0; rr < 4; rr++) {
        const size_t idx2 = (size_t)(row0 + (mf + 1) * 16 + rr) * 1024 + n;
        cpn[rr] = cprev[idx2];
        mkn[rr] = mask ? mask[idx2] : 1.0f;
      }
    }
    #pragma unroll
    for (int rr = 0; rr < 4; rr++) {
      const int row = row0 + mf * 16 + rr;
      const size_t idx = (size_t)row * 1024 + n;
      const float fg = sigm(acc[mf][0][rr] + bf_);
      const float ig = sigm(acc[mf][1][rr] + bi_);
      const float cg = tanh_(acc[mf][2][rr] + bc_);
      const float og = sigm(acc[mf][3][rr] + bo_);
      const float cn = fg * cp[rr] + ig * cg;
      const float hn = og * tanh_(cn);
      cout[idx] = cn;
      hout[idx] = hn;
      anext[(size_t)row * ldan + n] = f2b(hn * mk[rr]);
    }
    #pragma unroll
    for (int rr = 0; rr < 4; rr++) { cp[rr] = cpn[rr]; mk[rr] = mkn[rr]; }
  }
}

// ---------------- launch ----------------

extern "C" void kernel_launch(void* const* d_in, const int* in_sizes, int n_in,
                              void* d_out, int out_size, void* d_ws, size_t ws_size,
                              hipStream_t stream) {
  (void)in_sizes; (void)n_in; (void)out_size; (void)ws_size;
  const float* x   = (const float*)d_in[0];
  const float* h0  = (const float*)d_in[1];
  const float* h1  = (const float*)d_in[2];
  const float* c0  = (const float*)d_in[3];
  const float* c1  = (const float*)d_in[4];
  const float* m0  = (const float*)d_in[5];
  const float* m1  = (const float*)d_in[6];
  const float* Wf0 = (const float*)d_in[7];  const float* bf0 = (const float*)d_in[8];
  const float* Wi0 = (const float*)d_in[9];  const float* bi0 = (const float*)d_in[10];
  const float* Wc0 = (const float*)d_in[11]; const float* bc0 = (const float*)d_in[12];
  const float* Wo0 = (const float*)d_in[13]; const float* bo0 = (const float*)d_in[14];
  const float* Wf1 = (const float*)d_in[15]; const float* bf1 = (const float*)d_in[16];
  const float* Wi1 = (const float*)d_in[17]; const float* bi1 = (const float*)d_in[18];
  const float* Wc1 = (const float*)d_in[19]; const float* bc1 = (const float*)d_in[20];
  const float* Wo1 = (const float*)d_in[21]; const float* bo1 = (const float*)d_in[22];
  const float* Wm1 = (const float*)d_in[23]; const float* bm1 = (const float*)d_in[24];
  const float* Wm2 = (const float*)d_in[25]; const float* bm2 = (const float*)d_in[26];

  float* dout  = (float*)d_out;
  float* out_o = dout;                    // [8192,256]
  float* h0n   = dout + 2097152;          // [8192,1024]
  float* h1n   = h0n + 8388608;
  float* c0n   = h1n + 8388608;
  float* c1n   = c0n + 8388608;

  char* ws = (char*)d_ws;
  short* A0   = (short*)(ws);              // 8192x1536 bf16
  short* A1   = (short*)(ws + 25165824);   // 8192x2048
  short* A2   = (short*)(ws + 58720256);   // 8192x1024
  short* WT0  = (short*)(ws + 75497472);   // 4096x1536 (gate-interleaved B^T)
  short* WT1  = (short*)(ws + 88080384);   // 4096x2048
  short* Wm1b = (short*)(ws + 104857600);  // 1024x2048
  short* Wm2T = (short*)(ws + 109051904);  // 256x2048
  short* WpT  = (short*)(ws + 110100480);  // 256x1024
  float* bp   = (float*)(ws + 110624768);  // 256

  // ---- prep (3 launches) ----
  conv_acts<<<dim3(8192), dim3(320), 0, stream>>>(x, h0, m0, h1, m1, A0, A1);
  transpose_all<<<dim3(32, 16, 8), dim3(256), 0, stream>>>(
      Wf0, Wi0, Wc0, Wo0, Wf1, Wi1, Wc1, Wo1, WT0, WT1);
  mlp_prep<<<dim3(1168), dim3(256), 0, stream>>>(Wm1, Wm1b, Wm2, Wm2T, bm1, bm2, bp);

  // ---- collapsed MLP weight: WpT = (Wm1@Wm2)^T ----
  gemm_bt0<<<dim3(2, 8), dim3(256), 0, stream>>>(Wm2T, Wm1b, 2048, WpT, 1024);

  // ---- layer 0: h0n,c0n + A1[:, :1024] = bf16(h0n*m0) ----
  gemm8_lstm<<<dim3(32, 16), dim3(512), 0, stream>>>(
      A0, WT0, 1536, c0, h0n, c0n, A1, 2048, m0, bf0, bi0, bc0, bo0);

  // ---- layer 1: h1n,c1n + A2 = bf16(h1n) ----
  gemm8_lstm<<<dim3(32, 16), dim3(512), 0, stream>>>(
      A1, WT1, 2048, c1, h1n, c1n, A2, 1024, nullptr, bf1, bi1, bc1, bo1);

  // ---- output: out = h1n @ Wp + bp (64x128 tiles, 256 blocks) ----
  gemm_out<<<dim3(128, 2), dim3(256), 0, stream>>>(A2, WpT, 1024, out_o, bp);
}

// Round 15
// 391.305 us; speedup vs baseline: 1.0472x; 1.0472x over previous
//
#include <hip/hip_runtime.h>
#include <hip/hip_bf16.h>
#include <cstdint>
#include <cstddef>

#define DI __device__ __forceinline__

typedef __attribute__((ext_vector_type(8))) short short8;
typedef __attribute__((ext_vector_type(4))) float f32x4;

static constexpr int Bb = 8192, Dd = 512, Hh = 1024;

DI short f2b(float f) {
  union { __hip_bfloat16 h; short s; } u;
  u.h = __float2bfloat16(f);
  return u.s;
}

DI float sigm(float x) {
  float e = __builtin_amdgcn_exp2f(-1.4426950408889634f * x);
  return __builtin_amdgcn_rcpf(1.0f + e);
}
DI float tanh_(float x) {
  float xc = fminf(fmaxf(x, -20.0f), 20.0f);
  float e = __builtin_amdgcn_exp2f(-2.8853900817779268f * xc);  // exp(-2x)
  return (1.0f - e) * __builtin_amdgcn_rcpf(1.0f + e);
}

DI void gload16(const void* g, void* l) {
  __builtin_amdgcn_global_load_lds(
      (const __attribute__((address_space(1))) uint32_t*)g,
      (__attribute__((address_space(3))) uint32_t*)l, 16, 0, 0);
}

// ---------------- prep kernels ----------------

// fused: A0[row] = [x | h0*m0] (192 thr) and A1[row][1024:] = h1*m1 (128 thr)
__global__ void conv_acts(const float* __restrict__ x, const float* __restrict__ h0,
                          const float* __restrict__ m0, const float* __restrict__ h1,
                          const float* __restrict__ m1,
                          short* __restrict__ A0, short* __restrict__ A1) {
  const int row = blockIdx.x, t = threadIdx.x;  // block=320
  float v[8];
  if (t < 192) {
    if (t < 64) {
      const float4* p = (const float4*)(x + (size_t)row * Dd + t * 8);
      float4 a = p[0], b = p[1];
      v[0] = a.x; v[1] = a.y; v[2] = a.z; v[3] = a.w;
      v[4] = b.x; v[5] = b.y; v[6] = b.z; v[7] = b.w;
    } else {
      const int j = t * 8 - 512;
      const float4* ph = (const float4*)(h0 + (size_t)row * Hh + j);
      const float4* pm = (const float4*)(m0 + (size_t)row * Hh + j);
      float4 a = ph[0], b = ph[1], ma = pm[0], mb = pm[1];
      v[0] = a.x * ma.x; v[1] = a.y * ma.y; v[2] = a.z * ma.z; v[3] = a.w * ma.w;
      v[4] = b.x * mb.x; v[5] = b.y * mb.y; v[6] = b.z * mb.z; v[7] = b.w * mb.w;
    }
    short8 o;
    #pragma unroll
    for (int q = 0; q < 8; q++) o[q] = f2b(v[q]);
    *(short8*)(A0 + (size_t)row * 1536 + t * 8) = o;
  } else {
    const int j = (t - 192) * 8;
    const float4* ph = (const float4*)(h1 + (size_t)row * Hh + j);
    const float4* pm = (const float4*)(m1 + (size_t)row * Hh + j);
    float4 a = ph[0], b = ph[1], ma = pm[0], mb = pm[1];
    v[0] = a.x * ma.x; v[1] = a.y * ma.y; v[2] = a.z * ma.z; v[3] = a.w * ma.w;
    v[4] = b.x * mb.x; v[5] = b.y * mb.y; v[6] = b.z * mb.z; v[7] = b.w * mb.w;
    short8 o;
    #pragma unroll
    for (int q = 0; q < 8; q++) o[q] = f2b(v[q]);
    *(short8*)(A1 + (size_t)row * 2048 + 1024 + j) = o;
  }
}

// all 8 gate-weight transposes in one launch: z = layer*4 + gate
__global__ void transpose_all(
    const float* __restrict__ w00, const float* __restrict__ w01,
    const float* __restrict__ w02, const float* __restrict__ w03,
    const float* __restrict__ w10, const float* __restrict__ w11,
    const float* __restrict__ w12, const float* __restrict__ w13,
    short* __restrict__ WT0, short* __restrict__ WT1) {
  __shared__ float t[64][65];
  const int z = blockIdx.z;
  const int layer = z >> 2, g = z & 3;
  const int K = layer ? 2048 : 1536;
  const int k0 = blockIdx.x * 64;
  if (k0 >= K) return;
  const float* src;
  switch (z) {
    case 0: src = w00; break; case 1: src = w01; break;
    case 2: src = w02; break; case 3: src = w03; break;
    case 4: src = w10; break; case 5: src = w11; break;
    case 6: src = w12; break; default: src = w13; break;
  }
  short* dst = layer ? WT1 : WT0;
  const int n0 = blockIdx.y * 64;
  const int tid = threadIdx.x;           // 256
  const int r = tid >> 2, c0 = (tid & 3) * 16;
  const float* s = src + (size_t)(k0 + r) * 1024 + n0 + c0;
  #pragma unroll
  for (int q = 0; q < 16; q += 4) {
    float4 v = *(const float4*)(s + q);
    t[r][c0 + q + 0] = v.x; t[r][c0 + q + 1] = v.y;
    t[r][c0 + q + 2] = v.z; t[r][c0 + q + 3] = v.w;
  }
  __syncthreads();
  const int n = n0 + r;
  const int j = (n >> 4) * 64 + g * 16 + (n & 15);
  short8 o0, o1;
  #pragma unroll
  for (int q = 0; q < 8; q++) o0[q] = f2b(t[c0 + q][r]);
  #pragma unroll
  for (int q = 0; q < 8; q++) o1[q] = f2b(t[c0 + 8 + q][r]);
  short* d = dst + (size_t)j * K + k0 + c0;
  *(short8*)d = o0;
  *((short8*)d + 1) = o1;
}

// fused MLP prep: [0,1024) Wm1->bf16 | [1024,1152) Wm2^T | [1152,1168) bp
__global__ void mlp_prep(const float* __restrict__ Wm1, short* __restrict__ Wm1b,
                         const float* __restrict__ Wm2, short* __restrict__ Wm2T,
                         const float* __restrict__ bm1, const float* __restrict__ bm2,
                         float* __restrict__ bp) {
  __shared__ float t[64][65];
  const int b = blockIdx.x, tid = threadIdx.x;
  if (b < 1024) {
    const int id = b * 256 + tid;          // 262144 groups of 8
    const float4* p = (const float4*)(Wm1 + (size_t)id * 8);
    float4 a = p[0], bb = p[1];
    short8 o;
    o[0] = f2b(a.x); o[1] = f2b(a.y); o[2] = f2b(a.z); o[3] = f2b(a.w);
    o[4] = f2b(bb.x); o[5] = f2b(bb.y); o[6] = f2b(bb.z); o[7] = f2b(bb.w);
    *(short8*)(Wm1b + (size_t)id * 8) = o;
  } else if (b < 1152) {
    const int b2 = b - 1024;
    const int k0 = (b2 & 31) * 64, n0 = (b2 >> 5) * 64;   // N=256, K=2048
    const int r = tid >> 2, c0 = (tid & 3) * 16;
    const float* s = Wm2 + (size_t)(k0 + r) * 256 + n0 + c0;
    #pragma unroll
    for (int q = 0; q < 16; q += 4) {
      float4 v = *(const float4*)(s + q);
      t[r][c0 + q + 0] = v.x; t[r][c0 + q + 1] = v.y;
      t[r][c0 + q + 2] = v.z; t[r][c0 + q + 3] = v.w;
    }
    __syncthreads();
    const int n = n0 + r;
    short8 o0, o1;
    #pragma unroll
    for (int q = 0; q < 8; q++) o0[q] = f2b(t[c0 + q][r]);
    #pragma unroll
    for (int q = 0; q < 8; q++) o1[q] = f2b(t[c0 + 8 + q][r]);
    short* d = Wm2T + (size_t)n * 2048 + k0 + c0;
    *(short8*)d = o0;
    *((short8*)d + 1) = o1;
  } else {
    // bp[o] = bm2[o] + sum_k bm1[k]*Wm2[k][o]; 16 blocks x 16 o each, no atomics
    __shared__ float red[16][17];
    const int o0 = (b - 1152) * 16;
    const int oo = tid & 15, kk = tid >> 4;   // 16 x 16
    float s = 0.f;
    const int kbase = kk * 128;
    #pragma unroll 4
    for (int k = 0; k < 128; k++)
      s += bm1[kbase + k] * Wm2[(size_t)(kbase + k) * 256 + o0 + oo];
    red[kk][oo] = s;
    __syncthreads();
    if (tid < 16) {
      float acc = bm2[o0 + tid];
      #pragma unroll
      for (int j = 0; j < 16; j++) acc += red[j][tid];
      bp[o0 + tid] = acc;
    }
  }
}

// ---------------- small GEMM (m97-style 128x128): WpT build only ----------------
__global__ __launch_bounds__(256) void gemm_bt0(
    const short* __restrict__ A, const short* __restrict__ Bt, int K,
    short* __restrict__ Cb, int ldc) {
  __shared__ __align__(16) short sA[128 * 32];
  __shared__ __align__(16) short sB[128 * 32];
  const int tid = threadIdx.x;
  const int lane = tid & 63;
  const int wave = tid >> 6;
  const int wm = wave >> 1, wn = wave & 1;
  const int bm = blockIdx.x, bn = blockIdx.y;
  const int lr = lane & 15, lq = lane >> 4;

  f32x4 acc[4][4] = {};

  const short* pA = A + ((size_t)(bm * 128 + (tid >> 2))) * K + (tid & 3) * 8;
  const short* pB = Bt + ((size_t)(bn * 128 + (tid >> 2))) * K + (tid & 3) * 8;
  short* lA = sA + tid * 8;
  short* lB = sB + tid * 8;
  const int aoff = (wm * 64 + lr) * 32 + lq * 8;
  const int boff = (wn * 64 + lr) * 32 + lq * 8;

  for (int k0 = 0; k0 < K; k0 += 32) {
    gload16(pA + k0, lA);
    gload16(pA + (size_t)64 * K + k0, lA + 2048);
    gload16(pB + k0, lB);
    gload16(pB + (size_t)64 * K + k0, lB + 2048);
    __syncthreads();
    short8 af[4], bv[4];
    #pragma unroll
    for (int m = 0; m < 4; m++) af[m] = *(const short8*)&sA[aoff + m * 512];
    #pragma unroll
    for (int n = 0; n < 4; n++) bv[n] = *(const short8*)&sB[boff + n * 512];
    #pragma unroll
    for (int m = 0; m < 4; m++)
      #pragma unroll
      for (int n = 0; n < 4; n++)
        acc[m][n] = __builtin_amdgcn_mfma_f32_16x16x32_bf16(af[m], bv[n], acc[m][n], 0, 0, 0);
    __syncthreads();
  }

  const int crow0 = bm * 128 + wm * 64 + lq * 4;
  const int ccol0 = bn * 128 + wn * 64 + lr;
  #pragma unroll
  for (int m = 0; m < 4; m++)
    #pragma unroll
    for (int r = 0; r < 4; r++) {
      const int row = crow0 + m * 16 + r;
      #pragma unroll
      for (int n = 0; n < 4; n++)
        Cb[(size_t)row * ldc + ccol0 + n * 16] = f2b(acc[m][n][r]);
    }
}

// ---------- output GEMM: 64x128 tile, 256 blocks ----------
__global__ __launch_bounds__(256) void gemm_out(
    const short* __restrict__ A, const short* __restrict__ Bt, int K,
    float* __restrict__ outp, const float* __restrict__ bpv) {
  __shared__ __align__(16) short sA[64 * 32];
  __shared__ __align__(16) short sB[128 * 32];
  const int tid = threadIdx.x;
  const int lane = tid & 63;
  const int wn = tid >> 6;                 // 4 waves, each 64 rows x 32 cols
  const int bm = blockIdx.x, bn = blockIdx.y;
  const int lr = lane & 15, lq = lane >> 4;

  f32x4 acc[4][2] = {};

  const short* pA = A + ((size_t)(bm * 64 + (tid >> 2))) * K + (tid & 3) * 8;
  const short* pB = Bt + ((size_t)(bn * 128 + (tid >> 2))) * K + (tid & 3) * 8;
  short* lA = sA + tid * 8;
  short* lB = sB + tid * 8;
  const int boff = (wn * 32 + lr) * 32 + lq * 8;

  for (int k0 = 0; k0 < K; k0 += 32) {
    gload16(pA + k0, lA);
    gload16(pB + k0, lB);
    gload16(pB + (size_t)64 * K + k0, lB + 2048);
    __syncthreads();
    short8 af[4], bv[2];
    #pragma unroll
    for (int m = 0; m < 4; m++) af[m] = *(const short8*)&sA[(m * 16 + lr) * 32 + lq * 8];
    #pragma unroll
    for (int n = 0; n < 2; n++) bv[n] = *(const short8*)&sB[boff + n * 512];
    #pragma unroll
    for (int m = 0; m < 4; m++)
      #pragma unroll
      for (int n = 0; n < 2; n++)
        acc[m][n] = __builtin_amdgcn_mfma_f32_16x16x32_bf16(af[m], bv[n], acc[m][n], 0, 0, 0);
    __syncthreads();
  }

  const int crow0 = bm * 64 + lq * 4;
  const int ccol0 = bn * 128 + wn * 32 + lr;
  float bvv[2];
  #pragma unroll
  for (int n = 0; n < 2; n++) bvv[n] = bpv[ccol0 + n * 16];
  #pragma unroll
  for (int m = 0; m < 4; m++)
    #pragma unroll
    for (int r = 0; r < 4; r++) {
      const int row = crow0 + m * 16 + r;
      #pragma unroll
      for (int n = 0; n < 2; n++)
        outp[(size_t)row * 256 + ccol0 + n * 16] = acc[m][n][r] + bvv[n];
    }
}

// -------- 256x256 8-phase LSTM GEMM (R8 structure, best measured) --------

#define STA(buf, h, kt) { const short* s_ = gA + (size_t)(h) * 64 * K + (size_t)(kt) * 64; \
    gload16(s_ + aS0, &sA[buf][h][tid * 8]);                                               \
    gload16(s_ + aS1, &sA[buf][h][4096 + tid * 8]); }
#define STB(buf, h, kt) { const short* s_ = gB + (size_t)(h) * 128 * K + (size_t)(kt) * 64; \
    gload16(s_ + bS0, &sB[buf][h][tid * 8]);                                                \
    gload16(s_ + bS1, &sB[buf][h][4096 + tid * 8]); }

#define LDB(buf) {                                                \
    const short* bb = &sB[buf][bh][brb];                          \
    _Pragma("unroll") for (int n = 0; n < 4; n++) {               \
      bv[n][0] = *(const short8*)(bb + n * 1024 + sw0);           \
      bv[n][1] = *(const short8*)(bb + n * 1024 + sw1); } }

#define LDA_(buf, q, av) {                                        \
    const short* ab = &sA[buf][(q) >> 1][arb + ((q) & 1) * 2048]; \
    av[0][0] = *(const short8*)(ab + sw0);                        \
    av[0][1] = *(const short8*)(ab + sw1);                        \
    av[1][0] = *(const short8*)(ab + 1024 + sw0);                 \
    av[1][1] = *(const short8*)(ab + 1024 + sw1); }

#define MM(q, av) {                                               \
    __builtin_amdgcn_s_setprio(1);                                \
    _Pragma("unroll") for (int m = 0; m < 2; m++)                 \
    _Pragma("unroll") for (int n = 0; n < 4; n++) {               \
      acc[2*(q)+m][n] = __builtin_amdgcn_mfma_f32_16x16x32_bf16(av[m][0], bv[n][0], acc[2*(q)+m][n], 0, 0, 0); \
      acc[2*(q)+m][n] = __builtin_amdgcn_mfma_f32_16x16x32_bf16(av[m][1], bv[n][1], acc[2*(q)+m][n], 0, 0, 0); } \
    __builtin_amdgcn_s_setprio(0); }

#define BARR() __builtin_amdgcn_s_barrier()
#define VM6()  asm volatile("s_waitcnt vmcnt(6)")
#define LG8()  asm volatile("s_waitcnt lgkmcnt(8)")
#define LG0()  asm volatile("s_waitcnt lgkmcnt(0)")

#define PH(buf, q, STG, vm) { short8 av[2][2]; LDA_(buf, q, av); STG; \
    if (vm) VM6(); BARR(); LG0(); MM(q, av); BARR(); }

__global__ __launch_bounds__(512, 2) void gemm8_lstm(
    const short* __restrict__ A, const short* __restrict__ Bt, const int K,
    const float* __restrict__ cprev, float* __restrict__ hout,
    float* __restrict__ cout, short* __restrict__ anext, const int ldan,
    const float* __restrict__ mask,
    const float* __restrict__ bF, const float* __restrict__ bI,
    const float* __restrict__ bC, const float* __restrict__ bO) {
  __shared__ __align__(16) short sA[2][2][8192];
  __shared__ __align__(16) short sB[2][2][8192];
  const int tid = threadIdx.x;
  const int lane = tid & 63, wid = tid >> 6;
  const int wr = wid >> 2, wc = wid & 3;
  const int lr = lane & 15, lq = lane >> 4;
  const int bm = blockIdx.x, bn = blockIdx.y;

  const int NT = K >> 6;        // BK=64 tiles
  const int NIT = NT >> 1;

  // staging source offsets (inverse-swizzled global addresses)
  const int r0 = tid >> 3;
  const int csw = (tid & 7) ^ (r0 & 7);
  const int growA0 = ((r0 >> 5) & 1) * 32 + (r0 & 31);
  const int growA1 = 128 + growA0;
  const size_t aS0 = (size_t)growA0 * K + csw * 8;
  const size_t aS1 = (size_t)growA1 * K + csw * 8;
  const size_t bS0 = (size_t)r0 * K + csw * 8;
  const size_t bS1 = (size_t)(r0 + 64) * K + csw * 8;
  const short* gA = A + (size_t)bm * 256 * K;
  const short* gB = Bt + (size_t)bn * 256 * K;

  // ds_read offsets
  const int arb = (wr * 64 + lr) * 64;
  const int brb = ((wc & 1) * 64 + lr) * 64;
  const int bh = wc >> 1;
  const int sw0 = ((lq) ^ (lr & 7)) * 8;
  const int sw1 = ((4 + lq) ^ (lr & 7)) * 8;

  f32x4 acc[8][4] = {};
  short8 bv[4][2];

  // prologue: buf0 full (8 loads) + buf1 {B0,B1,A0} (6 loads); wait buf0
  STB(0, 0, 0); STB(0, 1, 0); STA(0, 0, 0); STA(0, 1, 0);
  STB(1, 0, 1); STB(1, 1, 1); STA(1, 0, 1);
  VM6(); BARR();

  for (int it = 0; it < NIT; ++it) {
    const int k1 = 2 * it + 1;
    int t2 = 2 * it + 2; if (t2 >= NT) t2 = 0;
    int t3 = 2 * it + 3; if (t3 >= NT) t3 = 1;
    // P1 (12 ds_reads): B-frags + q0 of buf0; stage buf1.A1(k1)
    { short8 av[2][2]; LDB(0); LDA_(0, 0, av); STA(1, 1, k1);
      LG8(); BARR(); LG0(); MM(0, av); BARR(); }
    PH(0, 1, STB(0, 0, t2), 0);   // P2
    PH(0, 2, STB(0, 1, t2), 0);   // P3
    PH(0, 3, STA(0, 0, t2), 1);   // P4: vm6 -> buf1 fully landed
    // P5 (12 ds_reads): B-frags + q0 of buf1; stage buf0.A1(t2)
    { short8 av[2][2]; LDB(1); LDA_(1, 0, av); STA(0, 1, t2);
      LG8(); BARR(); LG0(); MM(0, av); BARR(); }
    PH(1, 1, STB(1, 0, t3), 0);   // P6
    PH(1, 2, STB(1, 1, t3), 0);   // P7
    PH(1, 3, STA(1, 0, t3), 1);   // P8: vm6 -> buf0 (t2) fully landed
  }

  // ---- LSTM cell epilogue: fast math + pipelined cprev/mask prefetch ----
  const int n = (bn * 4 + wc) * 16 + lr;
  const float bf_ = bF[n], bi_ = bI[n], bc_ = bC[n], bo_ = bO[n];
  const int row0 = bm * 256 + wr * 128 + lq * 4;

  float cp[4], mk[4], cpn[4], mkn[4];
  #pragma unroll
  for (int rr = 0; rr < 4; rr++) {
    const size_t idx = (size_t)(row0 + rr) * 1024 + n;
    cp[rr] = cprev[idx];
    mk[rr] = mask ? mask[idx] : 1.0f;
  }
  #pragma unroll
  for (int mf = 0; mf < 8; mf++) {
    if (mf < 7) {
      #pragma unroll
      for (int rr = 0; rr < 4; rr++) {
        const size_t idx2 = (size_t)(row0 + (mf + 1) * 16 + rr) * 1024 + n;
        cpn[rr] = cprev[idx2];
        mkn[rr] = mask ? mask[idx2] : 1.0f;
      }
    }
    #pragma unroll
    for (int rr = 0; rr < 4; rr++) {
      const int row = row0 + mf * 16 + rr;
      const size_t idx = (size_t)row * 1024 + n;
      const float fg = sigm(acc[mf][0][rr] + bf_);
      const float ig = sigm(acc[mf][1][rr] + bi_);
      const float cg = tanh_(acc[mf][2][rr] + bc_);
      const float og = sigm(acc[mf][3][rr] + bo_);
      const float cn = fg * cp[rr] + ig * cg;
      const float hn = og * tanh_(cn);
      cout[idx] = cn;
      hout[idx] = hn;
      anext[(size_t)row * ldan + n] = f2b(hn * mk[rr]);
    }
    #pragma unroll
    for (int rr = 0; rr < 4; rr++) { cp[rr] = cpn[rr]; mk[rr] = mkn[rr]; }
  }
}

// ---------------- launch ----------------

extern "C" void kernel_launch(void* const* d_in, const int* in_sizes, int n_in,
                              void* d_out, int out_size, void* d_ws, size_t ws_size,
                              hipStream_t stream) {
  (void)in_sizes; (void)n_in; (void)out_size; (void)ws_size;
  const float* x   = (const float*)d_in[0];
  const float* h0  = (const float*)d_in[1];
  const float* h1  = (const float*)d_in[2];
  const float* c0  = (const float*)d_in[3];
  const float* c1  = (const float*)d_in[4];
  const float* m0  = (const float*)d_in[5];
  const float* m1  = (const float*)d_in[6];
  const float* Wf0 = (const float*)d_in[7];  const float* bf0 = (const float*)d_in[8];
  const float* Wi0 = (const float*)d_in[9];  const float* bi0 = (const float*)d_in[10];
  const float* Wc0 = (const float*)d_in[11]; const float* bc0 = (const float*)d_in[12];
  const float* Wo0 = (const float*)d_in[13]; const float* bo0 = (const float*)d_in[14];
  const float* Wf1 = (const float*)d_in[15]; const float* bf1 = (const float*)d_in[16];
  const float* Wi1 = (const float*)d_in[17]; const float* bi1 = (const float*)d_in[18];
  const float* Wc1 = (const float*)d_in[19]; const float* bc1 = (const float*)d_in[20];
  const float* Wo1 = (const float*)d_in[21]; const float* bo1 = (const float*)d_in[22];
  const float* Wm1 = (const float*)d_in[23]; const float* bm1 = (const float*)d_in[24];
  const float* Wm2 = (const float*)d_in[25]; const float* bm2 = (const float*)d_in[26];

  float* dout  = (float*)d_out;
  float* out_o = dout;                    // [8192,256]
  float* h0n   = dout + 2097152;          // [8192,1024]
  float* h1n   = h0n + 8388608;
  float* c0n   = h1n + 8388608;
  float* c1n   = c0n + 8388608;

  char* ws = (char*)d_ws;
  short* A0   = (short*)(ws);              // 8192x1536 bf16
  short* A1   = (short*)(ws + 25165824);   // 8192x2048
  short* A2   = (short*)(ws + 58720256);   // 8192x1024
  short* WT0  = (short*)(ws + 75497472);   // 4096x1536 (gate-interleaved B^T)
  short* WT1  = (short*)(ws + 88080384);   // 4096x2048
  short* Wm1b = (short*)(ws + 104857600);  // 1024x2048
  short* Wm2T = (short*)(ws + 109051904);  // 256x2048
  short* WpT  = (short*)(ws + 110100480);  // 256x1024
  float* bp   = (float*)(ws + 110624768);  // 256

  // ---- prep (3 launches) ----
  conv_acts<<<dim3(8192), dim3(320), 0, stream>>>(x, h0, m0, h1, m1, A0, A1);
  transpose_all<<<dim3(32, 16, 8), dim3(256), 0, stream>>>(
      Wf0, Wi0, Wc0, Wo0, Wf1, Wi1, Wc1, Wo1, WT0, WT1);
  mlp_prep<<<dim3(1168), dim3(256), 0, stream>>>(Wm1, Wm1b, Wm2, Wm2T, bm1, bm2, bp);

  // ---- collapsed MLP weight: WpT = (Wm1@Wm2)^T ----
  gemm_bt0<<<dim3(2, 8), dim3(256), 0, stream>>>(Wm2T, Wm1b, 2048, WpT, 1024);

  // ---- layer 0: h0n,c0n + A1[:, :1024] = bf16(h0n*m0) ----
  gemm8_lstm<<<dim3(32, 16), dim3(512), 0, stream>>>(
      A0, WT0, 1536, c0, h0n, c0n, A1, 2048, m0, bf0, bi0, bc0, bo0);

  // ---- layer 1: h1n,c1n + A2 = bf16(h1n) ----
  gemm8_lstm<<<dim3(32, 16), dim3(512), 0, stream>>>(
      A1, WT1, 2048, c1, h1n, c1n, A2, 1024, nullptr, bf1, bi1, bc1, bo1);

  // ---- output: out = h1n @ Wp + bp (64x128 tiles, 256 blocks) ----
  gemm_out<<<dim3(128, 2), dim3(256), 0, stream>>>(A2, WpT, 1024, out_o, bp);
}

// Round 16
// 375.227 us; speedup vs baseline: 1.0921x; 1.0428x over previous
//
#include <hip/hip_runtime.h>
#include <hip/hip_bf16.h>
#include <cstdint>
#include <cstddef>

#define DI __device__ __forceinline__

typedef __attribute__((ext_vector_type(8))) short short8;
typedef __attribute__((ext_vector_type(4))) float f32x4;

static constexpr int Bb = 8192, Dd = 512, Hh = 1024;

DI short f2b(float f) {
  union { __hip_bfloat16 h; short s; } u;
  u.h = __float2bfloat16(f);
  return u.s;
}

DI float sigm(float x) {
  float e = __builtin_amdgcn_exp2f(-1.4426950408889634f * x);
  return __builtin_amdgcn_rcpf(1.0f + e);
}
DI float tanh_(float x) {
  float xc = fminf(fmaxf(x, -20.0f), 20.0f);
  float e = __builtin_amdgcn_exp2f(-2.8853900817779268f * xc);  // exp(-2x)
  return (1.0f - e) * __builtin_amdgcn_rcpf(1.0f + e);
}

DI void gload16(const void* g, void* l) {
  __builtin_amdgcn_global_load_lds(
      (const __attribute__((address_space(1))) uint32_t*)g,
      (__attribute__((address_space(3))) uint32_t*)l, 16, 0, 0);
}

// ---------------- fused prep: ONE launch ----------------
// b <  8192           : conv_acts row b (320 threads active)
// 8192 <= b < 12288   : gate-weight transpose (z=(b-8192)>>9, 256 active)
// 12288 <= b < 13456  : mlp prep (Wm1 conv | Wm2^T | bp), 256 active
// Barrier safety: every __syncthreads is reached by ALL 320 threads
// (inactive lanes skip guarded loads/stores); early returns are block-uniform.
__global__ void prep_all(
    const float* __restrict__ x, const float* __restrict__ h0,
    const float* __restrict__ m0, const float* __restrict__ h1,
    const float* __restrict__ m1, short* __restrict__ A0, short* __restrict__ A1,
    const float* __restrict__ w00, const float* __restrict__ w01,
    const float* __restrict__ w02, const float* __restrict__ w03,
    const float* __restrict__ w10, const float* __restrict__ w11,
    const float* __restrict__ w12, const float* __restrict__ w13,
    short* __restrict__ WT0, short* __restrict__ WT1,
    const float* __restrict__ Wm1, short* __restrict__ Wm1b,
    const float* __restrict__ Wm2, short* __restrict__ Wm2T,
    const float* __restrict__ bm1, const float* __restrict__ bm2,
    float* __restrict__ bp) {
  const int b = blockIdx.x, t = threadIdx.x;   // block = 320

  if (b < 8192) {                 // ---- activations convert ----
    const int row = b;
    float v[8];
    if (t < 192) {
      if (t < 64) {
        const float4* p = (const float4*)(x + (size_t)row * Dd + t * 8);
        float4 a = p[0], bb = p[1];
        v[0] = a.x; v[1] = a.y; v[2] = a.z; v[3] = a.w;
        v[4] = bb.x; v[5] = bb.y; v[6] = bb.z; v[7] = bb.w;
      } else {
        const int j = t * 8 - 512;
        const float4* ph = (const float4*)(h0 + (size_t)row * Hh + j);
        const float4* pm = (const float4*)(m0 + (size_t)row * Hh + j);
        float4 a = ph[0], bb = ph[1], ma = pm[0], mb = pm[1];
        v[0] = a.x * ma.x; v[1] = a.y * ma.y; v[2] = a.z * ma.z; v[3] = a.w * ma.w;
        v[4] = bb.x * mb.x; v[5] = bb.y * mb.y; v[6] = bb.z * mb.z; v[7] = bb.w * mb.w;
      }
      short8 o;
      #pragma unroll
      for (int q = 0; q < 8; q++) o[q] = f2b(v[q]);
      *(short8*)(A0 + (size_t)row * 1536 + t * 8) = o;
    } else {
      const int j = (t - 192) * 8;
      const float4* ph = (const float4*)(h1 + (size_t)row * Hh + j);
      const float4* pm = (const float4*)(m1 + (size_t)row * Hh + j);
      float4 a = ph[0], bb = ph[1], ma = pm[0], mb = pm[1];
      v[0] = a.x * ma.x; v[1] = a.y * ma.y; v[2] = a.z * ma.z; v[3] = a.w * ma.w;
      v[4] = bb.x * mb.x; v[5] = bb.y * mb.y; v[6] = bb.z * mb.z; v[7] = bb.w * mb.w;
      short8 o;
      #pragma unroll
      for (int q = 0; q < 8; q++) o[q] = f2b(v[q]);
      *(short8*)(A1 + (size_t)row * 2048 + 1024 + j) = o;
    }
    return;
  }

  __shared__ float sh[64][65];

  if (b < 12288) {                // ---- gate weight transposes ----
    const int idx = b - 8192;
    const int z = idx >> 9, rem = idx & 511;
    const int layer = z >> 2, g = z & 3;
    const int K = layer ? 2048 : 1536;
    const int k0 = (rem & 31) * 64;
    if (k0 >= K) return;          // block-uniform
    const int n0 = (rem >> 5) * 64;
    const float* src;
    switch (z) {
      case 0: src = w00; break; case 1: src = w01; break;
      case 2: src = w02; break; case 3: src = w03; break;
      case 4: src = w10; break; case 5: src = w11; break;
      case 6: src = w12; break; default: src = w13; break;
    }
    short* dst = layer ? WT1 : WT0;
    const int r = t >> 2, c0 = (t & 3) * 16;
    if (t < 256) {
      const float* s = src + (size_t)(k0 + r) * 1024 + n0 + c0;
      #pragma unroll
      for (int q = 0; q < 16; q += 4) {
        float4 v = *(const float4*)(s + q);
        sh[r][c0 + q + 0] = v.x; sh[r][c0 + q + 1] = v.y;
        sh[r][c0 + q + 2] = v.z; sh[r][c0 + q + 3] = v.w;
      }
    }
    __syncthreads();
    if (t < 256) {
      const int n = n0 + r;
      const int j = (n >> 4) * 64 + g * 16 + (n & 15);
      short8 o0, o1;
      #pragma unroll
      for (int q = 0; q < 8; q++) o0[q] = f2b(sh[c0 + q][r]);
      #pragma unroll
      for (int q = 0; q < 8; q++) o1[q] = f2b(sh[c0 + 8 + q][r]);
      short* d = dst + (size_t)j * K + k0 + c0;
      *(short8*)d = o0;
      *((short8*)d + 1) = o1;
    }
    return;
  }

  const int b2 = b - 12288;       // ---- MLP prep ----
  if (b2 < 1024) {
    if (t < 256) {
      const int id = b2 * 256 + t;
      const float4* p = (const float4*)(Wm1 + (size_t)id * 8);
      float4 a = p[0], bb = p[1];
      short8 o;
      o[0] = f2b(a.x); o[1] = f2b(a.y); o[2] = f2b(a.z); o[3] = f2b(a.w);
      o[4] = f2b(bb.x); o[5] = f2b(bb.y); o[6] = f2b(bb.z); o[7] = f2b(bb.w);
      *(short8*)(Wm1b + (size_t)id * 8) = o;
    }
    return;
  }
  if (b2 < 1152) {
    const int b3 = b2 - 1024;
    const int k0 = (b3 & 31) * 64, n0 = (b3 >> 5) * 64;   // N=256, K=2048
    const int r = t >> 2, c0 = (t & 3) * 16;
    if (t < 256) {
      const float* s = Wm2 + (size_t)(k0 + r) * 256 + n0 + c0;
      #pragma unroll
      for (int q = 0; q < 16; q += 4) {
        float4 v = *(const float4*)(s + q);
        sh[r][c0 + q + 0] = v.x; sh[r][c0 + q + 1] = v.y;
        sh[r][c0 + q + 2] = v.z; sh[r][c0 + q + 3] = v.w;
      }
    }
    __syncthreads();
    if (t < 256) {
      const int n = n0 + r;
      short8 o0, o1;
      #pragma unroll
      for (int q = 0; q < 8; q++) o0[q] = f2b(sh[c0 + q][r]);
      #pragma unroll
      for (int q = 0; q < 8; q++) o1[q] = f2b(sh[c0 + 8 + q][r]);
      short* d = Wm2T + (size_t)n * 2048 + k0 + c0;
      *(short8*)d = o0;
      *((short8*)d + 1) = o1;
    }
    return;
  }
  {
    __shared__ float red[16][17];
    const int o0 = (b2 - 1152) * 16;
    if (t < 256) {
      const int oo = t & 15, kk = t >> 4;   // 16 x 16
      float s = 0.f;
      const int kbase = kk * 128;
      #pragma unroll 4
      for (int k = 0; k < 128; k++)
        s += bm1[kbase + k] * Wm2[(size_t)(kbase + k) * 256 + o0 + oo];
      red[kk][oo] = s;
    }
    __syncthreads();
    if (t < 16) {
      float acc = bm2[o0 + t];
      #pragma unroll
      for (int j = 0; j < 16; j++) acc += red[j][t];
      bp[o0 + t] = acc;
    }
  }
}

// ---------------- small GEMM (m97-style 128x128): WpT build only ----------------
__global__ __launch_bounds__(256) void gemm_bt0(
    const short* __restrict__ A, const short* __restrict__ Bt, int K,
    short* __restrict__ Cb, int ldc) {
  __shared__ __align__(16) short sA[128 * 32];
  __shared__ __align__(16) short sB[128 * 32];
  const int tid = threadIdx.x;
  const int lane = tid & 63;
  const int wave = tid >> 6;
  const int wm = wave >> 1, wn = wave & 1;
  const int bm = blockIdx.x, bn = blockIdx.y;
  const int lr = lane & 15, lq = lane >> 4;

  f32x4 acc[4][4] = {};

  const short* pA = A + ((size_t)(bm * 128 + (tid >> 2))) * K + (tid & 3) * 8;
  const short* pB = Bt + ((size_t)(bn * 128 + (tid >> 2))) * K + (tid & 3) * 8;
  short* lA = sA + tid * 8;
  short* lB = sB + tid * 8;
  const int aoff = (wm * 64 + lr) * 32 + lq * 8;
  const int boff = (wn * 64 + lr) * 32 + lq * 8;

  for (int k0 = 0; k0 < K; k0 += 32) {
    gload16(pA + k0, lA);
    gload16(pA + (size_t)64 * K + k0, lA + 2048);
    gload16(pB + k0, lB);
    gload16(pB + (size_t)64 * K + k0, lB + 2048);
    __syncthreads();
    short8 af[4], bv[4];
    #pragma unroll
    for (int m = 0; m < 4; m++) af[m] = *(const short8*)&sA[aoff + m * 512];
    #pragma unroll
    for (int n = 0; n < 4; n++) bv[n] = *(const short8*)&sB[boff + n * 512];
    #pragma unroll
    for (int m = 0; m < 4; m++)
      #pragma unroll
      for (int n = 0; n < 4; n++)
        acc[m][n] = __builtin_amdgcn_mfma_f32_16x16x32_bf16(af[m], bv[n], acc[m][n], 0, 0, 0);
    __syncthreads();
  }

  const int crow0 = bm * 128 + wm * 64 + lq * 4;
  const int ccol0 = bn * 128 + wn * 64 + lr;
  #pragma unroll
  for (int m = 0; m < 4; m++)
    #pragma unroll
    for (int r = 0; r < 4; r++) {
      const int row = crow0 + m * 16 + r;
      #pragma unroll
      for (int n = 0; n < 4; n++)
        Cb[(size_t)row * ldc + ccol0 + n * 16] = f2b(acc[m][n][r]);
    }
}

// ---------- output GEMM: 64x128 tile, 256 blocks ----------
__global__ __launch_bounds__(256) void gemm_out(
    const short* __restrict__ A, const short* __restrict__ Bt, int K,
    float* __restrict__ outp, const float* __restrict__ bpv) {
  __shared__ __align__(16) short sA[64 * 32];
  __shared__ __align__(16) short sB[128 * 32];
  const int tid = threadIdx.x;
  const int lane = tid & 63;
  const int wn = tid >> 6;                 // 4 waves, each 64 rows x 32 cols
  const int bm = blockIdx.x, bn = blockIdx.y;
  const int lr = lane & 15, lq = lane >> 4;

  f32x4 acc[4][2] = {};

  const short* pA = A + ((size_t)(bm * 64 + (tid >> 2))) * K + (tid & 3) * 8;
  const short* pB = Bt + ((size_t)(bn * 128 + (tid >> 2))) * K + (tid & 3) * 8;
  short* lA = sA + tid * 8;
  short* lB = sB + tid * 8;
  const int boff = (wn * 32 + lr) * 32 + lq * 8;

  for (int k0 = 0; k0 < K; k0 += 32) {
    gload16(pA + k0, lA);
    gload16(pB + k0, lB);
    gload16(pB + (size_t)64 * K + k0, lB + 2048);
    __syncthreads();
    short8 af[4], bv[2];
    #pragma unroll
    for (int m = 0; m < 4; m++) af[m] = *(const short8*)&sA[(m * 16 + lr) * 32 + lq * 8];
    #pragma unroll
    for (int n = 0; n < 2; n++) bv[n] = *(const short8*)&sB[boff + n * 512];
    #pragma unroll
    for (int m = 0; m < 4; m++)
      #pragma unroll
      for (int n = 0; n < 2; n++)
        acc[m][n] = __builtin_amdgcn_mfma_f32_16x16x32_bf16(af[m], bv[n], acc[m][n], 0, 0, 0);
    __syncthreads();
  }

  const int crow0 = bm * 64 + lq * 4;
  const int ccol0 = bn * 128 + wn * 32 + lr;
  float bvv[2];
  #pragma unroll
  for (int n = 0; n < 2; n++) bvv[n] = bpv[ccol0 + n * 16];
  #pragma unroll
  for (int m = 0; m < 4; m++)
    #pragma unroll
    for (int r = 0; r < 4; r++) {
      const int row = crow0 + m * 16 + r;
      #pragma unroll
      for (int n = 0; n < 2; n++)
        outp[(size_t)row * 256 + ccol0 + n * 16] = acc[m][n][r] + bvv[n];
    }
}

// -------- 256x256 8-phase LSTM GEMM (R8 structure, best measured) --------

#define STA(buf, h, kt) { const short* s_ = gA + (size_t)(h) * 64 * K + (size_t)(kt) * 64; \
    gload16(s_ + aS0, &sA[buf][h][tid * 8]);                                               \
    gload16(s_ + aS1, &sA[buf][h][4096 + tid * 8]); }
#define STB(buf, h, kt) { const short* s_ = gB + (size_t)(h) * 128 * K + (size_t)(kt) * 64; \
    gload16(s_ + bS0, &sB[buf][h][tid * 8]);                                                \
    gload16(s_ + bS1, &sB[buf][h][4096 + tid * 8]); }

#define LDB(buf) {                                                \
    const short* bb = &sB[buf][bh][brb];                          \
    _Pragma("unroll") for (int n = 0; n < 4; n++) {               \
      bv[n][0] = *(const short8*)(bb + n * 1024 + sw0);           \
      bv[n][1] = *(const short8*)(bb + n * 1024 + sw1); } }

#define LDA_(buf, q, av) {                                        \
    const short* ab = &sA[buf][(q) >> 1][arb + ((q) & 1) * 2048]; \
    av[0][0] = *(const short8*)(ab + sw0);                        \
    av[0][1] = *(const short8*)(ab + sw1);                        \
    av[1][0] = *(const short8*)(ab + 1024 + sw0);                 \
    av[1][1] = *(const short8*)(ab + 1024 + sw1); }

#define MM(q, av) {                                               \
    __builtin_amdgcn_s_setprio(1);                                \
    _Pragma("unroll") for (int m = 0; m < 2; m++)                 \
    _Pragma("unroll") for (int n = 0; n < 4; n++) {               \
      acc[2*(q)+m][n] = __builtin_amdgcn_mfma_f32_16x16x32_bf16(av[m][0], bv[n][0], acc[2*(q)+m][n], 0, 0, 0); \
      acc[2*(q)+m][n] = __builtin_amdgcn_mfma_f32_16x16x32_bf16(av[m][1], bv[n][1], acc[2*(q)+m][n], 0, 0, 0); } \
    __builtin_amdgcn_s_setprio(0); }

#define BARR() __builtin_amdgcn_s_barrier()
#define VM6()  asm volatile("s_waitcnt vmcnt(6)")
#define LG8()  asm volatile("s_waitcnt lgkmcnt(8)")
#define LG0()  asm volatile("s_waitcnt lgkmcnt(0)")

#define PH(buf, q, STG, vm) { short8 av[2][2]; LDA_(buf, q, av); STG; \
    if (vm) VM6(); BARR(); LG0(); MM(q, av); BARR(); }

__global__ __launch_bounds__(512, 2) void gemm8_lstm(
    const short* __restrict__ A, const short* __restrict__ Bt, const int K,
    const float* __restrict__ cprev, float* __restrict__ hout,
    float* __restrict__ cout, short* __restrict__ anext, const int ldan,
    const float* __restrict__ mask,
    const float* __restrict__ bF, const float* __restrict__ bI,
    const float* __restrict__ bC, const float* __restrict__ bO) {
  __shared__ __align__(16) short sA[2][2][8192];
  __shared__ __align__(16) short sB[2][2][8192];
  const int tid = threadIdx.x;
  const int lane = tid & 63, wid = tid >> 6;
  const int wr = wid >> 2, wc = wid & 3;
  const int lr = lane & 15, lq = lane >> 4;
  const int bm = blockIdx.x, bn = blockIdx.y;

  const int NT = K >> 6;        // BK=64 tiles
  const int NIT = NT >> 1;

  // staging source offsets (inverse-swizzled global addresses)
  const int r0 = tid >> 3;
  const int csw = (tid & 7) ^ (r0 & 7);
  const int growA0 = ((r0 >> 5) & 1) * 32 + (r0 & 31);
  const int growA1 = 128 + growA0;
  const size_t aS0 = (size_t)growA0 * K + csw * 8;
  const size_t aS1 = (size_t)growA1 * K + csw * 8;
  const size_t bS0 = (size_t)r0 * K + csw * 8;
  const size_t bS1 = (size_t)(r0 + 64) * K + csw * 8;
  const short* gA = A + (size_t)bm * 256 * K;
  const short* gB = Bt + (size_t)bn * 256 * K;

  // ds_read offsets
  const int arb = (wr * 64 + lr) * 64;
  const int brb = ((wc & 1) * 64 + lr) * 64;
  const int bh = wc >> 1;
  const int sw0 = ((lq) ^ (lr & 7)) * 8;
  const int sw1 = ((4 + lq) ^ (lr & 7)) * 8;

  f32x4 acc[8][4] = {};
  short8 bv[4][2];

  // prologue: buf0 full (8 loads) + buf1 {B0,B1,A0} (6 loads); wait buf0
  STB(0, 0, 0); STB(0, 1, 0); STA(0, 0, 0); STA(0, 1, 0);
  STB(1, 0, 1); STB(1, 1, 1); STA(1, 0, 1);
  VM6(); BARR();

  for (int it = 0; it < NIT; ++it) {
    const int k1 = 2 * it + 1;
    int t2 = 2 * it + 2; if (t2 >= NT) t2 = 0;
    int t3 = 2 * it + 3; if (t3 >= NT) t3 = 1;
    // P1 (12 ds_reads): B-frags + q0 of buf0; stage buf1.A1(k1)
    { short8 av[2][2]; LDB(0); LDA_(0, 0, av); STA(1, 1, k1);
      LG8(); BARR(); LG0(); MM(0, av); BARR(); }
    PH(0, 1, STB(0, 0, t2), 0);   // P2
    PH(0, 2, STB(0, 1, t2), 0);   // P3
    PH(0, 3, STA(0, 0, t2), 1);   // P4: vm6 -> buf1 fully landed
    // P5 (12 ds_reads): B-frags + q0 of buf1; stage buf0.A1(t2)
    { short8 av[2][2]; LDB(1); LDA_(1, 0, av); STA(0, 1, t2);
      LG8(); BARR(); LG0(); MM(0, av); BARR(); }
    PH(1, 1, STB(1, 0, t3), 0);   // P6
    PH(1, 2, STB(1, 1, t3), 0);   // P7
    PH(1, 3, STA(1, 0, t3), 1);   // P8: vm6 -> buf0 (t2) fully landed
  }

  // ---- LSTM cell epilogue: fast math + pipelined cprev/mask prefetch ----
  const int n = (bn * 4 + wc) * 16 + lr;
  const float bf_ = bF[n], bi_ = bI[n], bc_ = bC[n], bo_ = bO[n];
  const int row0 = bm * 256 + wr * 128 + lq * 4;

  float cp[4], mk[4], cpn[4], mkn[4];
  #pragma unroll
  for (int rr = 0; rr < 4; rr++) {
    const size_t idx = (size_t)(row0 + rr) * 1024 + n;
    cp[rr] = cprev[idx];
    mk[rr] = mask ? mask[idx] : 1.0f;
  }
  #pragma unroll
  for (int mf = 0; mf < 8; mf++) {
    if (mf < 7) {
      #pragma unroll
      for (int rr = 0; rr < 4; rr++) {
        const size_t idx2 = (size_t)(row0 + (mf + 1) * 16 + rr) * 1024 + n;
        cpn[rr] = cprev[idx2];
        mkn[rr] = mask ? mask[idx2] : 1.0f;
      }
    }
    #pragma unroll
    for (int rr = 0; rr < 4; rr++) {
      const int row = row0 + mf * 16 + rr;
      const size_t idx = (size_t)row * 1024 + n;
      const float fg = sigm(acc[mf][0][rr] + bf_);
      const float ig = sigm(acc[mf][1][rr] + bi_);
      const float cg = tanh_(acc[mf][2][rr] + bc_);
      const float og = sigm(acc[mf][3][rr] + bo_);
      const float cn = fg * cp[rr] + ig * cg;
      const float hn = og * tanh_(cn);
      cout[idx] = cn;
      hout[idx] = hn;
      anext[(size_t)row * ldan + n] = f2b(hn * mk[rr]);
    }
    #pragma unroll
    for (int rr = 0; rr < 4; rr++) { cp[rr] = cpn[rr]; mk[rr] = mkn[rr]; }
  }
}

// ---------------- launch ----------------

extern "C" void kernel_launch(void* const* d_in, const int* in_sizes, int n_in,
                              void* d_out, int out_size, void* d_ws, size_t ws_size,
                              hipStream_t stream) {
  (void)in_sizes; (void)n_in; (void)out_size; (void)ws_size;
  const float* x   = (const float*)d_in[0];
  const float* h0  = (const float*)d_in[1];
  const float* h1  = (const float*)d_in[2];
  const float* c0  = (const float*)d_in[3];
  const float* c1  = (const float*)d_in[4];
  const float* m0  = (const float*)d_in[5];
  const float* m1  = (const float*)d_in[6];
  const float* Wf0 = (const float*)d_in[7];  const float* bf0 = (const float*)d_in[8];
  const float* Wi0 = (const float*)d_in[9];  const float* bi0 = (const float*)d_in[10];
  const float* Wc0 = (const float*)d_in[11]; const float* bc0 = (const float*)d_in[12];
  const float* Wo0 = (const float*)d_in[13]; const float* bo0 = (const float*)d_in[14];
  const float* Wf1 = (const float*)d_in[15]; const float* bf1 = (const float*)d_in[16];
  const float* Wi1 = (const float*)d_in[17]; const float* bi1 = (const float*)d_in[18];
  const float* Wc1 = (const float*)d_in[19]; const float* bc1 = (const float*)d_in[20];
  const float* Wo1 = (const float*)d_in[21]; const float* bo1 = (const float*)d_in[22];
  const float* Wm1 = (const float*)d_in[23]; const float* bm1 = (const float*)d_in[24];
  const float* Wm2 = (const float*)d_in[25]; const float* bm2 = (const float*)d_in[26];

  float* dout  = (float*)d_out;
  float* out_o = dout;                    // [8192,256]
  float* h0n   = dout + 2097152;          // [8192,1024]
  float* h1n   = h0n + 8388608;
  float* c0n   = h1n + 8388608;
  float* c1n   = c0n + 8388608;

  char* ws = (char*)d_ws;
  short* A0   = (short*)(ws);              // 8192x1536 bf16
  short* A1   = (short*)(ws + 25165824);   // 8192x2048
  short* A2   = (short*)(ws + 58720256);   // 8192x1024
  short* WT0  = (short*)(ws + 75497472);   // 4096x1536 (gate-interleaved B^T)
  short* WT1  = (short*)(ws + 88080384);   // 4096x2048
  short* Wm1b = (short*)(ws + 104857600);  // 1024x2048
  short* Wm2T = (short*)(ws + 109051904);  // 256x2048
  short* WpT  = (short*)(ws + 110100480);  // 256x1024
  float* bp   = (float*)(ws + 110624768);  // 256

  // ---- prep: ONE launch ----
  prep_all<<<dim3(13456), dim3(320), 0, stream>>>(
      x, h0, m0, h1, m1, A0, A1,
      Wf0, Wi0, Wc0, Wo0, Wf1, Wi1, Wc1, Wo1, WT0, WT1,
      Wm1, Wm1b, Wm2, Wm2T, bm1, bm2, bp);

  // ---- collapsed MLP weight: WpT = (Wm1@Wm2)^T ----
  gemm_bt0<<<dim3(2, 8), dim3(256), 0, stream>>>(Wm2T, Wm1b, 2048, WpT, 1024);

  // ---- layer 0: h0n,c0n + A1[:, :1024] = bf16(h0n*m0) ----
  gemm8_lstm<<<dim3(32, 16), dim3(512), 0, stream>>>(
      A0, WT0, 1536, c0, h0n, c0n, A1, 2048, m0, bf0, bi0, bc0, bo0);

  // ---- layer 1: h1n,c1n + A2 = bf16(h1n) ----
  gemm8_lstm<<<dim3(32, 16), dim3(512), 0, stream>>>(
      A1, WT1, 2048, c1, h1n, c1n, A2, 1024, nullptr, bf1, bi1, bc1, bo1);

  // ---- output: out = h1n @ Wp + bp (64x128 tiles, 256 blocks) ----
  gemm_out<<<dim3(128, 2), dim3(256), 0, stream>>>(A2, WpT, 1024, out_o, bp);
}